// Round 2
// baseline (144.527 us; speedup 1.0000x reference)
//
#include <hip/hip_runtime.h>
#include <hip/hip_bf16.h>

#define M_DIM 64
#define K_DIM 8192
#define N_DIM 10240

typedef __attribute__((ext_vector_type(8))) short short8;
typedef __attribute__((ext_vector_type(4))) float f32x4;

// exact for integer-valued floats |v| <= 127 (<= 7 significant bits)
static __device__ __forceinline__ ushort f2bf_trunc(float f) {
    return (ushort)(__float_as_uint(f) >> 16);
}

// ---------------- Kernel 1: per-token dynamic int8 quantization ----------------
// one block per row m; x is float32 [64, 8192]; writes xq (bf16-encoded ints in
// [-127,127]) and per-row scale (f32).
__global__ __launch_bounds__(256) void quant_kernel(
    const float* __restrict__ x,
    ushort* __restrict__ xq,
    float* __restrict__ xscale) {
    const int m = blockIdx.x;
    const int tid = threadIdx.x;
    const float4* xrow = (const float4*)(x + m * K_DIM);  // 2048 x float4
    float4 c[8];
    float mx = 0.f;
#pragma unroll
    for (int i = 0; i < 8; ++i) {
        c[i] = xrow[i * 256 + tid];
        mx = fmaxf(mx, fmaxf(fmaxf(fabsf(c[i].x), fabsf(c[i].y)),
                             fmaxf(fabsf(c[i].z), fabsf(c[i].w))));
    }
#pragma unroll
    for (int off = 32; off; off >>= 1) mx = fmaxf(mx, __shfl_xor(mx, off));
    __shared__ float wmax[4];
    if ((tid & 63) == 0) wmax[tid >> 6] = mx;
    __syncthreads();
    mx = fmaxf(fmaxf(wmax[0], wmax[1]), fmaxf(wmax[2], wmax[3]));
    const float s = mx / 127.0f;  // matches reference x_scale exactly
    if (tid == 0) xscale[m] = s;

    ushort4* qrow = (ushort4*)(xq + m * K_DIM);
#pragma unroll
    for (int i = 0; i < 8; ++i) {
        float q0 = fminf(fmaxf(rintf(c[i].x / s), -127.f), 127.f);
        float q1 = fminf(fmaxf(rintf(c[i].y / s), -127.f), 127.f);
        float q2 = fminf(fmaxf(rintf(c[i].z / s), -127.f), 127.f);
        float q3 = fminf(fmaxf(rintf(c[i].w / s), -127.f), 127.f);
        ushort4 o;
        o.x = f2bf_trunc(q0);
        o.y = f2bf_trunc(q1);
        o.z = f2bf_trunc(q2);
        o.w = f2bf_trunc(q3);
        qrow[i * 256 + tid] = o;
    }
}

// ---------------- Kernel 2: int8-as-bf16 MFMA GEMM + fused dequant -------------
// grid = N/16 blocks, 4 waves/block; wave w handles K-range [w*2048, w*2048+2048)
// (split-K within block, LDS reduce). Each wave: 16 N-cols x 64 M-rows.
__global__ __launch_bounds__(256) void gemm_kernel(
    const ushort* __restrict__ xq,      // bf16 bits [64, 8192]
    const float* __restrict__ xscale,   // [64]
    const int* __restrict__ W,          // int32 [10240, 8192], values in [-127,127]
    const float* __restrict__ wscale,   // [10240]
    const float* __restrict__ bias,     // f32 [10240]
    float* __restrict__ out) {          // f32 [64, 10240]
    const int tid = threadIdx.x;
    const int wave = tid >> 6;
    const int lane = tid & 63;
    const int r16 = lane & 15;
    const int kgrp = lane >> 4;
    const int n0 = blockIdx.x << 4;

    f32x4 acc[4];
#pragma unroll
    for (int i = 0; i < 4; ++i) acc[i] = (f32x4){0.f, 0.f, 0.f, 0.f};

    const int kbeg = wave * (K_DIM / 4) + kgrp * 8;
    const int* wp = W + (size_t)(n0 + r16) * K_DIM + kbeg;
    const ushort* ap = xq + r16 * K_DIM + kbeg;

#pragma unroll 2
    for (int it = 0; it < 64; ++it) {
        int4 b0 = *(const int4*)(wp);
        int4 b1 = *(const int4*)(wp + 4);
        short8 a0 = *(const short8*)(ap);
        short8 a1 = *(const short8*)(ap + 16 * K_DIM);
        short8 a2 = *(const short8*)(ap + 32 * K_DIM);
        short8 a3 = *(const short8*)(ap + 48 * K_DIM);
        int wv[8] = {b0.x, b0.y, b0.z, b0.w, b1.x, b1.y, b1.z, b1.w};
        short8 bf;
#pragma unroll
        for (int i = 0; i < 8; ++i)
            bf[i] = (short)(__float_as_uint((float)wv[i]) >> 16);  // exact, |v|<=127
        acc[0] = __builtin_amdgcn_mfma_f32_16x16x32_bf16(a0, bf, acc[0], 0, 0, 0);
        acc[1] = __builtin_amdgcn_mfma_f32_16x16x32_bf16(a1, bf, acc[1], 0, 0, 0);
        acc[2] = __builtin_amdgcn_mfma_f32_16x16x32_bf16(a2, bf, acc[2], 0, 0, 0);
        acc[3] = __builtin_amdgcn_mfma_f32_16x16x32_bf16(a3, bf, acc[3], 0, 0, 0);
        wp += 32;
        ap += 32;
    }

    // cross-wave split-K reduce in LDS
    __shared__ float red[4][64][16];
#pragma unroll
    for (int mt = 0; mt < 4; ++mt)
#pragma unroll
        for (int j = 0; j < 4; ++j)
            red[wave][mt * 16 + kgrp * 4 + j][r16] = acc[mt][j];
    __syncthreads();

#pragma unroll
    for (int i = 0; i < 4; ++i) {
        int flat = tid + 256 * i;  // 0..1023 -> (m, nl)
        int m = flat >> 4;
        int nl = flat & 15;
        float sum = red[0][m][nl] + red[1][m][nl] + red[2][m][nl] + red[3][m][nl];
        int n = n0 + nl;
        float o = sum * xscale[m] * wscale[n] + bias[n];
        out[m * N_DIM + n] = o;
    }
}

extern "C" void kernel_launch(void* const* d_in, const int* in_sizes, int n_in,
                              void* d_out, int out_size, void* d_ws, size_t ws_size,
                              hipStream_t stream) {
    const float* x = (const float*)d_in[0];
    const int* W = (const int*)d_in[1];
    const float* wscale = (const float*)d_in[2];
    const float* bias = (const float*)d_in[3];
    float* out = (float*)d_out;

    float* xscale = (float*)d_ws;
    ushort* xq = (ushort*)((char*)d_ws + 256);

    quant_kernel<<<64, 256, 0, stream>>>(x, xq, xscale);
    gemm_kernel<<<N_DIM / 16, 256, 0, stream>>>(xq, xscale, W, wscale, bias, out);
}